// Round 2
// baseline (173.328 us; speedup 1.0000x reference)
//
#include <hip/hip_runtime.h>
#include <hip/hip_bf16.h>

// ---- problem constants ----
#define T_DIM   2048
#define A_DIM   64
#define N_TOK   (T_DIM * A_DIM)     // 131072
#define RAWOB   120
#define N_TP    5
#define E_EXP   10
#define D_DIM   126                  // RAWOB + N_TP + 1
#define DP      128                  // padded K
#define H_DIM   128
#define N_ACT   16
#define CAP     16384                // per-expert bucket capacity (max count ~13.6K, 30 sigma margin)
#define MAXC    (CAP / 128)          // 128 chunks per expert
#define LOGITS_SZ (N_TOK * N_ACT)    // 2097152
#define XS_STRIDE 136                // padded LDS row stride (16B aligned)

typedef __bf16 bh8 __attribute__((ext_vector_type(8)));
typedef float  f32x4 __attribute__((ext_vector_type(4)));

__device__ __forceinline__ f32x4 mfma16(bh8 a, bh8 b, f32x4 c) {
    return __builtin_amdgcn_mfma_f32_16x16x32_bf16(a, b, c, 0, 0, 0);
}

__device__ __forceinline__ float bf2f(ushort u) {
    unsigned x = ((unsigned)u) << 16;
    return __builtin_bit_cast(float, x);
}
__device__ __forceinline__ ushort f2bf(float f) {
    unsigned x = __builtin_bit_cast(unsigned, f);
    unsigned r = (x + 0x7fffu + ((x >> 16) & 1u)) >> 16;   // round-nearest-even
    return (ushort)r;
}

// ---------------- kernel 0: weight transpose f32 -> bf16 + counter zero ----------------
// W1t[e][h][d] (d-contiguous, d padded to 128 w/ zeros), W2t[e][a][h], Wc1t[h][d]
#define W1T_N (E_EXP * H_DIM * DP)           // 163840
#define W2T_N (E_EXP * N_ACT * H_DIM)        // 20480
#define WC1T_N (DP * DP)                     // 16384
#define PREP_TOTAL (W1T_N + W2T_N + WC1T_N)  // 200704

__global__ __launch_bounds__(256) void prep_kernel(
    const float* __restrict__ W1, const float* __restrict__ W2,
    const float* __restrict__ Wc1,
    int* __restrict__ counts, ushort* __restrict__ W1t,
    ushort* __restrict__ W2t, ushort* __restrict__ Wc1t)
{
    int i = blockIdx.x * 256 + threadIdx.x;
    if (i < 16) counts[i] = 0;
    if (i < W1T_N) {
        int e = i >> 14;          // / 16384
        int r = i & 16383;
        int h = r >> 7;
        int d = r & 127;
        W1t[i] = (d < D_DIM) ? f2bf(W1[(e * D_DIM + d) * H_DIM + h]) : (ushort)0;
    } else if (i < W1T_N + W2T_N) {
        int r = i - W1T_N;
        int e = r / (N_ACT * H_DIM);
        int q = r % (N_ACT * H_DIM);
        int a = q >> 7;
        int h = q & 127;
        W2t[r] = f2bf(W2[(e * H_DIM + h) * N_ACT + a]);
    } else if (i < PREP_TOTAL) {
        int r = i - W1T_N - W2T_N;
        int h = r >> 7;
        int d = r & 127;
        Wc1t[r] = (d < D_DIM) ? f2bf(Wc1[d * H_DIM + h]) : (ushort)0;
    }
}

// ---------------- kernel 1: bucket tokens by expert ----------------
__global__ __launch_bounds__(256) void bucket_kernel(
    const int* __restrict__ pick, int* __restrict__ counts, int* __restrict__ order)
{
    __shared__ int lc[E_EXP], lb[E_EXP], lcur[E_EXP];
    int t = threadIdx.x;
    if (t < E_EXP) { lc[t] = 0; lcur[t] = 0; }
    __syncthreads();
    int i = blockIdx.x * 256 + t;
    int e = pick[i];
    atomicAdd(&lc[e], 1);
    __syncthreads();
    if (t < E_EXP) lb[t] = atomicAdd(&counts[t], lc[t]);
    __syncthreads();
    int pos = lb[e] + atomicAdd(&lcur[e], 1);
    if (pos < CAP) order[e * CAP + pos] = i;
}

// ---------------- GEMM helper: [128 x 128(K)] @ Wt -> relu -> hs ----------------
// xs: LDS tokens [128][XS_STRIDE] bf16; Wt: global bf16 [n][k] k-contig, stride 128
__device__ __forceinline__ void gemm128_relu(
    const ushort* xs, const ushort* __restrict__ Wt,
    const float* __restrict__ bias, ushort* hs, int w, int l)
{
    const int n0 = w * 32;
    const int lm = l & 15;
    const int lq = l >> 4;

    f32x4 acc[8][2];
#pragma unroll
    for (int mt = 0; mt < 8; ++mt) {
        acc[mt][0] = (f32x4){0.f, 0.f, 0.f, 0.f};
        acc[mt][1] = (f32x4){0.f, 0.f, 0.f, 0.f};
    }
    bh8 bfrag[4][2];
#pragma unroll
    for (int kt = 0; kt < 4; ++kt)
#pragma unroll
        for (int nt = 0; nt < 2; ++nt)
            bfrag[kt][nt] = *(const bh8*)(const void*)
                (Wt + (n0 + nt * 16 + lm) * DP + kt * 32 + lq * 8);

#pragma unroll
    for (int kt = 0; kt < 4; ++kt) {
#pragma unroll
        for (int mt = 0; mt < 8; ++mt) {
            bh8 a = *(const bh8*)(const void*)
                (xs + (mt * 16 + lm) * XS_STRIDE + kt * 32 + lq * 8);
            acc[mt][0] = mfma16(a, bfrag[kt][0], acc[mt][0]);
            acc[mt][1] = mfma16(a, bfrag[kt][1], acc[mt][1]);
        }
    }
    float bn0 = bias[n0 + lm];
    float bn1 = bias[n0 + 16 + lm];
#pragma unroll
    for (int mt = 0; mt < 8; ++mt) {
#pragma unroll
        for (int nt = 0; nt < 2; ++nt) {
            float bn = nt ? bn1 : bn0;
            int n = n0 + nt * 16 + lm;
#pragma unroll
            for (int r = 0; r < 4; ++r) {
                int m = mt * 16 + lq * 4 + r;
                float vf = acc[mt][nt][r] + bn;
                vf = fmaxf(vf, 0.f);
                hs[m * XS_STRIDE + n] = f2bf(vf);
            }
        }
    }
}

// ---------------- kernel 2: per-expert MoE tile + critic ----------------
__global__ __launch_bounds__(256) void moe_kernel(
    const float* __restrict__ obs, const int* __restrict__ hete_type,
    const int* __restrict__ gp_sel,
    const float* __restrict__ b1, const float* __restrict__ b2,
    const float* __restrict__ bc1, const float* __restrict__ bc2,
    const int* __restrict__ counts, const int* __restrict__ order,
    const ushort* __restrict__ W1t, const ushort* __restrict__ W2t,
    const ushort* __restrict__ Wc1t, const float* __restrict__ Wc2,
    float* __restrict__ out)
{
    __shared__ int idx_s[128];
    __shared__ __align__(16) ushort xs[128 * XS_STRIDE];
    __shared__ __align__(16) ushort hs[128 * XS_STRIDE];
    __shared__ float wc2s[128];

    const int bx = blockIdx.x;
    const int e = bx % E_EXP;
    const int c = bx / E_EXP;
    const int cnt = counts[e];
    const int start = c * 128;
    if (start >= cnt) return;
    const int v = min(128, cnt - start);

    const int tid = threadIdx.x;
    if (tid < 128) {
        int tok = 0;
        if (tid < v) tok = order[e * CAP + start + tid];
        idx_s[tid] = tok;
    } else {
        wc2s[tid - 128] = Wc2[tid - 128];
    }
    __syncthreads();

    // ---- stage augmented x tile: rows = tokens, cols = D (padded 128), f32 -> bf16 ----
    const int ck = (tid & 15) * 8;   // column chunk base
    const int r0 = tid >> 4;         // row within group of 16
#pragma unroll
    for (int j = 0; j < 8; ++j) {
        int row = r0 + j * 16;
        int tok = idx_s[row];
        ushort* dst = &xs[row * XS_STRIDE + ck];
        if (ck < RAWOB) {
            const float* src = obs + tok * RAWOB + ck;
            float4 u0 = *(const float4*)(const void*)src;
            float4 u1 = *(const float4*)(const void*)(src + 4);
            dst[0] = f2bf(u0.x); dst[1] = f2bf(u0.y);
            dst[2] = f2bf(u0.z); dst[3] = f2bf(u0.w);
            dst[4] = f2bf(u1.x); dst[5] = f2bf(u1.y);
            dst[6] = f2bf(u1.z); dst[7] = f2bf(u1.w);
        } else {  // cols 120..127: [hete_type, gp_obs(5), 0, 0]
            int ht = hete_type[tok];
            int tt = tok >> 6;  // token / A_DIM
            dst[0] = f2bf((float)ht);
#pragma unroll
            for (int q = 0; q < N_TP; ++q) {
                float g = (q == ht) ? -1.0f : (float)gp_sel[tt * N_TP + q];
                dst[1 + q] = f2bf(g);
            }
            dst[6] = 0; dst[7] = 0;
        }
    }
    __syncthreads();

    const int w = tid >> 6;
    const int l = tid & 63;
    const int lm = l & 15;
    const int lq = l >> 4;

    // ---- expert layer 1: hs = relu(xs @ W1[e] + b1[e]) ----
    gemm128_relu(xs, W1t + e * DP * DP, b1 + e * H_DIM, hs, w, l);
    __syncthreads();

    // ---- expert layer 2: y = hs @ W2[e] + b2[e]  (N=16) ----
    {
        f32x4 acc2[2];
        acc2[0] = (f32x4){0.f, 0.f, 0.f, 0.f};
        acc2[1] = (f32x4){0.f, 0.f, 0.f, 0.f};
        bh8 bfrag[4];
#pragma unroll
        for (int kt = 0; kt < 4; ++kt)
            bfrag[kt] = *(const bh8*)(const void*)
                (W2t + (e * N_ACT + lm) * H_DIM + kt * 32 + lq * 8);
#pragma unroll
        for (int kt = 0; kt < 4; ++kt) {
#pragma unroll
            for (int i2 = 0; i2 < 2; ++i2) {
                int mt = w + i2 * 4;
                bh8 a = *(const bh8*)(const void*)
                    (hs + (mt * 16 + lm) * XS_STRIDE + kt * 32 + lq * 8);
                acc2[i2] = mfma16(a, bfrag[kt], acc2[i2]);
            }
        }
        float bb = b2[e * N_ACT + lm];
#pragma unroll
        for (int i2 = 0; i2 < 2; ++i2) {
            int mt = w + i2 * 4;
#pragma unroll
            for (int r = 0; r < 4; ++r) {
                int m = mt * 16 + lq * 4 + r;
                if (m < v) {
                    int tok = idx_s[m];
                    out[tok * N_ACT + lm] = acc2[i2][r] + bb;
                }
            }
        }
    }
    __syncthreads();  // all waves done reading hs before critic overwrites it

    // ---- critic layer 1: hs = relu(xs @ Wc1 + bc1) ----
    gemm128_relu(xs, Wc1t, bc1, hs, w, l);
    __syncthreads();

    // ---- critic layer 2: value = hs @ Wc2 + bc2  (N=1, vector reduce) ----
    {
        int m = tid >> 1;
        int half = tid & 1;
        const ushort* hr = &hs[m * XS_STRIDE + half * 64];
        const float* wr = &wc2s[half * 64];
        float s = 0.f;
#pragma unroll
        for (int n = 0; n < 64; ++n) s += bf2f(hr[n]) * wr[n];
        float so = __shfl_xor(s, 1, 64);
        float vt = s + so + bc2[0];
        if (half == 0 && m < v) {
            out[LOGITS_SZ + idx_s[m]] = vt;
        }
    }
}

extern "C" void kernel_launch(void* const* d_in, const int* in_sizes, int n_in,
                              void* d_out, int out_size, void* d_ws, size_t ws_size,
                              hipStream_t stream) {
    const float* obs  = (const float*)d_in[0];
    const int*   pick = (const int*)d_in[1];
    const int*   htyp = (const int*)d_in[2];
    const int*   gp   = (const int*)d_in[3];
    const float* W1   = (const float*)d_in[4];
    const float* b1   = (const float*)d_in[5];
    const float* W2   = (const float*)d_in[6];
    const float* b2   = (const float*)d_in[7];
    const float* Wc1  = (const float*)d_in[8];
    const float* bc1  = (const float*)d_in[9];
    const float* Wc2  = (const float*)d_in[10];
    const float* bc2  = (const float*)d_in[11];
    float* out = (float*)d_out;

    int*    counts = (int*)d_ws;              // 16 ints
    int*    order  = counts + 16;             // E_EXP * CAP ints
    ushort* W1t    = (ushort*)(order + E_EXP * CAP);
    ushort* W2t    = W1t + W1T_N;
    ushort* Wc1t   = W2t + W2T_N;

    prep_kernel<<<(PREP_TOTAL + 255) / 256, 256, 0, stream>>>(
        W1, W2, Wc1, counts, W1t, W2t, Wc1t);
    bucket_kernel<<<N_TOK / 256, 256, 0, stream>>>(pick, counts, order);
    moe_kernel<<<E_EXP * MAXC, 256, 0, stream>>>(
        obs, htyp, gp, b1, b2, bc1, bc2, counts, order,
        W1t, W2t, Wc1t, Wc2, out);
}

// Round 3
// 157.955 us; speedup vs baseline: 1.0973x; 1.0973x over previous
//
#include <hip/hip_runtime.h>
#include <hip/hip_bf16.h>

// ---- problem constants ----
#define T_DIM   2048
#define A_DIM   64
#define N_TOK   (T_DIM * A_DIM)     // 131072
#define RAWOB   120
#define N_TP    5
#define E_EXP   10
#define D_DIM   126                  // RAWOB + N_TP + 1
#define DP      128                  // padded K
#define H_DIM   128
#define N_ACT   16
#define CAP     16384                // per-expert bucket capacity (mean 13107 + 30 sigma)
#define MTILE   64                   // tokens per moe block (LDS 35.6KB -> 4 blocks/CU)
#define MAXC    (CAP / MTILE)        // 256 chunks per expert
#define LOGITS_SZ (N_TOK * N_ACT)    // 2097152
#define XS_STRIDE 136                // padded LDS row stride (16B aligned)

typedef __bf16 bh8 __attribute__((ext_vector_type(8)));
typedef float  f32x4 __attribute__((ext_vector_type(4)));

__device__ __forceinline__ f32x4 mfma16(bh8 a, bh8 b, f32x4 c) {
    return __builtin_amdgcn_mfma_f32_16x16x32_bf16(a, b, c, 0, 0, 0);
}

__device__ __forceinline__ float bf2f(ushort u) {
    unsigned x = ((unsigned)u) << 16;
    return __builtin_bit_cast(float, x);
}
__device__ __forceinline__ ushort f2bf(float f) {
    unsigned x = __builtin_bit_cast(unsigned, f);
    unsigned r = (x + 0x7fffu + ((x >> 16) & 1u)) >> 16;   // round-nearest-even
    return (ushort)r;
}

// ---------------- kernel 0: weight transpose f32 -> bf16 + counter zero ----------------
// W1t[e][h][d] (d-contig, d padded to 128 w/ zeros), W2t[e][a][h], Wc1t[h][d]
#define W1T_N (E_EXP * H_DIM * DP)           // 163840
#define W2T_N (E_EXP * N_ACT * H_DIM)        // 20480
#define WC1T_N (DP * DP)                     // 16384
// blocks: 0..39 W1 transpose (expert e = bx>>2, d-chunk (bx&3)*32)
//         40..43 Wc1 transpose
//         44..123 W2 naive (+ counts zero in bx 44)
#define PREP_BLOCKS 124

__global__ __launch_bounds__(256) void prep_kernel(
    const float* __restrict__ W1, const float* __restrict__ W2,
    const float* __restrict__ Wc1,
    int* __restrict__ counts, ushort* __restrict__ W1t,
    ushort* __restrict__ W2t, ushort* __restrict__ Wc1t)
{
    int bx = blockIdx.x, tid = threadIdx.x;
    if (bx < 44) {
        __shared__ ushort st[32][130];   // 32 d-rows x 128 h, padded
        const float* src;
        ushort* dstbase;
        int d0;
        if (bx < 40) {
            int e = bx >> 2;
            d0 = (bx & 3) * 32;
            src = W1 + (e * D_DIM + d0) * H_DIM;
            dstbase = W1t + e * H_DIM * DP;
        } else {
            d0 = (bx - 40) * 32;
            src = Wc1 + d0 * H_DIM;
            dstbase = Wc1t;
        }
        int dmax = D_DIM - d0;           // 32,32,32,30
#pragma unroll
        for (int p = 0; p < 16; ++p) {
            int idx = p * 256 + tid;
            int dd = idx >> 7, h = idx & 127;
            float v = (dd < dmax) ? src[dd * H_DIM + h] : 0.f;  // coalesced in h
            st[dd][h] = f2bf(v);
        }
        __syncthreads();
#pragma unroll
        for (int p = 0; p < 16; ++p) {
            int idx = p * 256 + tid;
            int h = idx >> 5, d = idx & 31;
            dstbase[h * DP + d0 + d] = st[d][h];                // 64B runs in d
        }
    } else {
        int i = (bx - 44) * 256 + tid;   // [0, 20480)
        int h = i & 127;
        int a = (i >> 7) & 15;
        int e = i >> 11;
        W2t[(e * N_ACT + a) * H_DIM + h] = f2bf(W2[(e * H_DIM + h) * N_ACT + a]);
        if (bx == 44 && tid < 160) counts[tid] = 0;
    }
}

// ---------------- kernel 1: bucket tokens by expert ----------------
// counts padded: expert e lives at counts[e*16] (own 64B line)
#define BUCKET_BLOCKS 128
__global__ __launch_bounds__(256) void bucket_kernel(
    const int* __restrict__ pick, int* __restrict__ counts, int* __restrict__ order)
{
    __shared__ int lc[E_EXP], lb[E_EXP], lcur[E_EXP];
    int tid = threadIdx.x;
    if (tid < E_EXP) { lc[tid] = 0; lcur[tid] = 0; }
    __syncthreads();
    int base = blockIdx.x * 1024;
    int e4[4];
#pragma unroll
    for (int it = 0; it < 4; ++it) {
        e4[it] = pick[base + it * 256 + tid];
        atomicAdd(&lc[e4[it]], 1);
    }
    __syncthreads();
    if (tid < E_EXP) lb[tid] = atomicAdd(&counts[tid * 16], lc[tid]);
    __syncthreads();
#pragma unroll
    for (int it = 0; it < 4; ++it) {
        int e = e4[it];
        int pos = lb[e] + atomicAdd(&lcur[e], 1);
        if (pos < CAP) order[e * CAP + pos] = base + it * 256 + tid;
    }
}

// ---------------- GEMM helper: [64 x 128(K)] @ Wt(128 n) -> relu -> hs ----------------
__device__ __forceinline__ void gemm64_relu(
    const ushort* xs, const ushort* __restrict__ Wt,
    const float* __restrict__ bias, ushort* hs, int w, int l)
{
    const int n0 = w * 32;
    const int lm = l & 15;
    const int lq = l >> 4;

    f32x4 acc[4][2];
#pragma unroll
    for (int mt = 0; mt < 4; ++mt) {
        acc[mt][0] = (f32x4){0.f, 0.f, 0.f, 0.f};
        acc[mt][1] = (f32x4){0.f, 0.f, 0.f, 0.f};
    }
    bh8 bfrag[4][2];
#pragma unroll
    for (int kt = 0; kt < 4; ++kt)
#pragma unroll
        for (int nt = 0; nt < 2; ++nt)
            bfrag[kt][nt] = *(const bh8*)(const void*)
                (Wt + (n0 + nt * 16 + lm) * DP + kt * 32 + lq * 8);

#pragma unroll
    for (int kt = 0; kt < 4; ++kt) {
#pragma unroll
        for (int mt = 0; mt < 4; ++mt) {
            bh8 a = *(const bh8*)(const void*)
                (xs + (mt * 16 + lm) * XS_STRIDE + kt * 32 + lq * 8);
            acc[mt][0] = mfma16(a, bfrag[kt][0], acc[mt][0]);
            acc[mt][1] = mfma16(a, bfrag[kt][1], acc[mt][1]);
        }
    }
    float bn0 = bias[n0 + lm];
    float bn1 = bias[n0 + 16 + lm];
#pragma unroll
    for (int mt = 0; mt < 4; ++mt) {
#pragma unroll
        for (int nt = 0; nt < 2; ++nt) {
            float bn = nt ? bn1 : bn0;
            int n = n0 + nt * 16 + lm;
#pragma unroll
            for (int r = 0; r < 4; ++r) {
                int m = mt * 16 + lq * 4 + r;
                float vf = acc[mt][nt][r] + bn;
                vf = fmaxf(vf, 0.f);
                hs[m * XS_STRIDE + n] = f2bf(vf);
            }
        }
    }
}

// ---------------- kernel 2: per-expert MoE tile + critic ----------------
__global__ __launch_bounds__(256) void moe_kernel(
    const float* __restrict__ obs, const int* __restrict__ hete_type,
    const int* __restrict__ gp_sel,
    const float* __restrict__ b1, const float* __restrict__ b2,
    const float* __restrict__ bc1, const float* __restrict__ bc2,
    const int* __restrict__ counts, const int* __restrict__ order,
    const ushort* __restrict__ W1t, const ushort* __restrict__ W2t,
    const ushort* __restrict__ Wc1t, const float* __restrict__ Wc2,
    float* __restrict__ out)
{
    __shared__ int idx_s[MTILE];
    __shared__ __align__(16) ushort xs[MTILE * XS_STRIDE];
    __shared__ __align__(16) ushort hs[MTILE * XS_STRIDE];
    __shared__ float wc2s[128];

    const int bx = blockIdx.x;
    const int e = bx % E_EXP;
    const int c = bx / E_EXP;
    const int cnt = counts[e * 16];
    const int start = c * MTILE;
    if (start >= cnt) return;
    const int v = min(MTILE, cnt - start);

    const int tid = threadIdx.x;
    if (tid < MTILE) {
        int tok = 0;
        if (tid < v) tok = order[e * CAP + start + tid];
        idx_s[tid] = tok;
    } else if (tid < MTILE + 128) {
        wc2s[tid - MTILE] = Wc2[tid - MTILE];
    }
    __syncthreads();

    // ---- stage augmented x tile: rows = tokens, cols = D (padded 128), f32 -> bf16 ----
    const int ck = (tid & 15) * 8;   // column chunk base
    const int r0 = tid >> 4;         // row within group of 16
#pragma unroll
    for (int j = 0; j < 4; ++j) {
        int row = r0 + j * 16;
        int tok = idx_s[row];
        ushort* dst = &xs[row * XS_STRIDE + ck];
        if (ck < RAWOB) {
            const float* src = obs + tok * RAWOB + ck;
            float4 u0 = *(const float4*)(const void*)src;
            float4 u1 = *(const float4*)(const void*)(src + 4);
            dst[0] = f2bf(u0.x); dst[1] = f2bf(u0.y);
            dst[2] = f2bf(u0.z); dst[3] = f2bf(u0.w);
            dst[4] = f2bf(u1.x); dst[5] = f2bf(u1.y);
            dst[6] = f2bf(u1.z); dst[7] = f2bf(u1.w);
        } else {  // cols 120..127: [hete_type, gp_obs(5), 0, 0]
            int ht = hete_type[tok];
            int tt = tok >> 6;  // token / A_DIM
            dst[0] = f2bf((float)ht);
#pragma unroll
            for (int q = 0; q < N_TP; ++q) {
                float g = (q == ht) ? -1.0f : (float)gp_sel[tt * N_TP + q];
                dst[1 + q] = f2bf(g);
            }
            dst[6] = 0; dst[7] = 0;
        }
    }
    __syncthreads();

    const int w = tid >> 6;
    const int l = tid & 63;
    const int lm = l & 15;
    const int lq = l >> 4;

    // ---- expert layer 1: hs = relu(xs @ W1[e] + b1[e]) ----
    gemm64_relu(xs, W1t + e * DP * DP, b1 + e * H_DIM, hs, w, l);
    __syncthreads();

    // ---- expert layer 2: y = hs @ W2[e] + b2[e]  (N=16) ----
    {
        f32x4 acc2 = (f32x4){0.f, 0.f, 0.f, 0.f};
        bh8 bfrag[4];
#pragma unroll
        for (int kt = 0; kt < 4; ++kt)
            bfrag[kt] = *(const bh8*)(const void*)
                (W2t + (e * N_ACT + lm) * H_DIM + kt * 32 + lq * 8);
#pragma unroll
        for (int kt = 0; kt < 4; ++kt) {
            bh8 a = *(const bh8*)(const void*)
                (hs + (w * 16 + lm) * XS_STRIDE + kt * 32 + lq * 8);
            acc2 = mfma16(a, bfrag[kt], acc2);
        }
        float bb = b2[e * N_ACT + lm];
#pragma unroll
        for (int r = 0; r < 4; ++r) {
            int m = w * 16 + lq * 4 + r;
            if (m < v) {
                int tok = idx_s[m];
                out[tok * N_ACT + lm] = acc2[r] + bb;
            }
        }
    }
    __syncthreads();  // all waves done reading hs before critic overwrites it

    // ---- critic layer 1: hs = relu(xs @ Wc1 + bc1) ----
    gemm64_relu(xs, Wc1t, bc1, hs, w, l);
    __syncthreads();

    // ---- critic layer 2: value = hs @ Wc2 + bc2  (N=1, vector reduce) ----
    if (tid < 128) {
        int m = tid >> 1;
        int half = tid & 1;
        const ushort* hr = &hs[m * XS_STRIDE + half * 64];
        const float* wr = &wc2s[half * 64];
        float s = 0.f;
#pragma unroll
        for (int n = 0; n < 64; ++n) s += bf2f(hr[n]) * wr[n];
        float so = __shfl_xor(s, 1, 64);
        float vt = s + so + bc2[0];
        if (half == 0 && m < v) {
            out[LOGITS_SZ + idx_s[m]] = vt;
        }
    }
}

extern "C" void kernel_launch(void* const* d_in, const int* in_sizes, int n_in,
                              void* d_out, int out_size, void* d_ws, size_t ws_size,
                              hipStream_t stream) {
    const float* obs  = (const float*)d_in[0];
    const int*   pick = (const int*)d_in[1];
    const int*   htyp = (const int*)d_in[2];
    const int*   gp   = (const int*)d_in[3];
    const float* W1   = (const float*)d_in[4];
    const float* b1   = (const float*)d_in[5];
    const float* W2   = (const float*)d_in[6];
    const float* b2   = (const float*)d_in[7];
    const float* Wc1  = (const float*)d_in[8];
    const float* bc1  = (const float*)d_in[9];
    const float* Wc2  = (const float*)d_in[10];
    const float* bc2  = (const float*)d_in[11];
    float* out = (float*)d_out;

    int*    counts = (int*)d_ws;              // 160 ints (padded, e -> counts[e*16])
    int*    order  = counts + 160;            // E_EXP * CAP ints
    ushort* W1t    = (ushort*)(order + E_EXP * CAP);
    ushort* W2t    = W1t + W1T_N;
    ushort* Wc1t   = W2t + W2T_N;

    prep_kernel<<<PREP_BLOCKS, 256, 0, stream>>>(
        W1, W2, Wc1, counts, W1t, W2t, Wc1t);
    bucket_kernel<<<BUCKET_BLOCKS, 256, 0, stream>>>(pick, counts, order);
    moe_kernel<<<E_EXP * MAXC, 256, 0, stream>>>(
        obs, htyp, gp, b1, b2, bc1, bc2, counts, order,
        W1t, W2t, Wc1t, Wc2, out);
}